// Round 1
// baseline (2254.341 us; speedup 1.0000x reference)
//
#include <hip/hip_runtime.h>

#define NN 50000
#define NE 800000
#define IND 256
#define HD 128
#define OD 64

__global__ void deg_init_k(float* __restrict__ deg) {
    int i = blockIdx.x * 256 + threadIdx.x;
    if (i < NN) deg[i] = 1.0f;   // self-loop contributes 1
}

__global__ void deg_count_k(const int* __restrict__ dst, float* __restrict__ deg) {
    int e = blockIdx.x * 256 + threadIdx.x;
    if (e < NE) atomicAdd(&deg[dst[e]], 1.0f);
}

__global__ void dinv_k(float* __restrict__ deg) {
    int i = blockIdx.x * 256 + threadIdx.x;
    if (i < NN) deg[i] = rsqrtf(deg[i]);  // deg >= 1 always (self-loops)
}

// Row-major f32 GEMM: C[M,N] = A[M,K] @ B[K,N].  TM must be 4.
template<int BM, int BN, int BK, int TM, int TN>
__launch_bounds__(256)
__global__ void gemm_k(const float* __restrict__ A, const float* __restrict__ B,
                       float* __restrict__ C, int M, int K, int N) {
    static_assert(TM == 4, "A-fragment read assumes TM==4");
    __shared__ float As[BK][BM + 4];   // +4 pad: keeps 16B alignment, breaks bank stride
    __shared__ float Bs[BK][BN];
    const int tid = threadIdx.x;
    const int tx = tid % (BN / TN);
    const int ty = tid / (BN / TN);
    const int m0 = blockIdx.x * BM;

    float acc[TM][TN];
#pragma unroll
    for (int r = 0; r < TM; ++r)
#pragma unroll
        for (int c = 0; c < TN; ++c) acc[r][c] = 0.0f;

    for (int k0 = 0; k0 < K; k0 += BK) {
        // Stage A tile (BM x BK), transposed into As[k][m]
#pragma unroll
        for (int idx = tid; idx < BM * BK / 4; idx += 256) {
            int m  = idx / (BK / 4);
            int kq = (idx % (BK / 4)) * 4;
            float4 v = make_float4(0.f, 0.f, 0.f, 0.f);
            if (m0 + m < M)
                v = *(const float4*)&A[(long)(m0 + m) * K + k0 + kq];
            As[kq + 0][m] = v.x;
            As[kq + 1][m] = v.y;
            As[kq + 2][m] = v.z;
            As[kq + 3][m] = v.w;
        }
        // Stage B tile (BK x BN), contiguous
#pragma unroll
        for (int idx = tid; idx < BK * BN / 4; idx += 256) {
            int k  = idx / (BN / 4);
            int nq = (idx % (BN / 4)) * 4;
            *(float4*)&Bs[k][nq] = *(const float4*)&B[(long)(k0 + k) * N + nq];
        }
        __syncthreads();

#pragma unroll
        for (int kk = 0; kk < BK; ++kk) {
            float a[TM];
            *(float4*)a = *(const float4*)&As[kk][ty * TM];
            float b[TN];
#pragma unroll
            for (int c = 0; c < TN; c += 4) {
                float4 bv = *(const float4*)&Bs[kk][tx * TN + c];
                b[c + 0] = bv.x; b[c + 1] = bv.y; b[c + 2] = bv.z; b[c + 3] = bv.w;
            }
#pragma unroll
            for (int r = 0; r < TM; ++r)
#pragma unroll
                for (int c = 0; c < TN; ++c)
                    acc[r][c] = fmaf(a[r], b[c], acc[r][c]);
        }
        __syncthreads();
    }

#pragma unroll
    for (int r = 0; r < TM; ++r) {
        int row = m0 + ty * TM + r;
        if (row < M) {
#pragma unroll
            for (int c = 0; c < TN; c += 4) {
                float4 o = make_float4(acc[r][c], acc[r][c + 1], acc[r][c + 2], acc[r][c + 3]);
                *(float4*)&C[(long)row * N + tx * TN + c] = o;
            }
        }
    }
}

// Edge-parallel scatter-add:  agg[dst] += feat[src] * dinv[src]*dinv[dst]
// One thread handles 4 contiguous columns of one edge.
template<int F>
__global__ void scatter_k(const float* __restrict__ feat, const int* __restrict__ src,
                          const int* __restrict__ dst, const float* __restrict__ dinv,
                          float* __restrict__ agg) {
    const int LPE = F / 4;
    int gid = blockIdx.x * 256 + threadIdx.x;
    int e = gid / LPE;
    if (e >= NE) return;
    int c = (gid % LPE) * 4;
    int s = src[e], d = dst[e];
    float nrm = dinv[s] * dinv[d];
    float4 v = *(const float4*)&feat[(long)s * F + c];
    atomicAdd(&agg[(long)d * F + c + 0], v.x * nrm);
    atomicAdd(&agg[(long)d * F + c + 1], v.y * nrm);
    atomicAdd(&agg[(long)d * F + c + 2], v.z * nrm);
    atomicAdd(&agg[(long)d * F + c + 3], v.w * nrm);
}

// epilogue: out = [relu](agg + feat*dinv^2 (self loop) + bias)
template<int F, bool RELU>
__global__ void post_k(const float* __restrict__ agg, const float* __restrict__ selff,
                       const float* __restrict__ dinv, const float* __restrict__ bias,
                       float* __restrict__ out) {
    const int total = NN * (F / 4);
    int i = blockIdx.x * 256 + threadIdx.x;
    if (i >= total) return;
    int row = i / (F / 4);
    int c = (i % (F / 4)) * 4;
    float di = dinv[row];
    float sl = di * di;
    float4 a = *(const float4*)&agg[(long)row * F + c];
    float4 s = *(const float4*)&selff[(long)row * F + c];
    float4 b = *(const float4*)&bias[c];
    float4 o;
    o.x = fmaf(s.x, sl, a.x) + b.x;
    o.y = fmaf(s.y, sl, a.y) + b.y;
    o.z = fmaf(s.z, sl, a.z) + b.z;
    o.w = fmaf(s.w, sl, a.w) + b.w;
    if (RELU) {
        o.x = fmaxf(o.x, 0.f); o.y = fmaxf(o.y, 0.f);
        o.z = fmaxf(o.z, 0.f); o.w = fmaxf(o.w, 0.f);
    }
    *(float4*)&out[(long)row * F + c] = o;
}

extern "C" void kernel_launch(void* const* d_in, const int* in_sizes, int n_in,
                              void* d_out, int out_size, void* d_ws, size_t ws_size,
                              hipStream_t stream) {
    const float* x   = (const float*)d_in[0];
    const int*   src = (const int*)d_in[1];            // edge_index[0]
    const int*   dst = ((const int*)d_in[1]) + NE;     // edge_index[1]
    const float* W1  = (const float*)d_in[2];
    const float* b1  = (const float*)d_in[3];
    const float* W2  = (const float*)d_in[4];
    const float* b2  = (const float*)d_in[5];
    float* out = (float*)d_out;

    float* ws   = (float*)d_ws;
    float* dinv = ws;                                   // 50048 floats (deg -> dinv in place)
    float* h1   = dinv + 50048;                         // [NN, HD]
    float* agg1 = h1   + (size_t)NN * HD;               // [NN, HD] -> becomes h after post
    float* g    = agg1 + (size_t)NN * HD;               // [NN, OD]
    float* agg2 = g    + (size_t)NN * OD;               // [NN, OD]

    // degree + normalization
    deg_init_k<<<(NN + 255) / 256, 256, 0, stream>>>(dinv);
    deg_count_k<<<(NE + 255) / 256, 256, 0, stream>>>(dst, dinv);
    dinv_k<<<(NN + 255) / 256, 256, 0, stream>>>(dinv);

    // layer 1: h1 = x @ W1
    gemm_k<64, 128, 32, 4, 8><<<(NN + 63) / 64, 256, 0, stream>>>(x, W1, h1, NN, IND, HD);
    hipMemsetAsync(agg1, 0, (size_t)NN * HD * sizeof(float), stream);
    scatter_k<HD><<<(NE * (HD / 4) + 255) / 256, 256, 0, stream>>>(h1, src, dst, dinv, agg1);
    post_k<HD, true><<<(NN * (HD / 4) + 255) / 256, 256, 0, stream>>>(agg1, h1, dinv, b1, agg1);

    // layer 2: g = h @ W2
    gemm_k<64, 64, 32, 4, 4><<<(NN + 63) / 64, 256, 0, stream>>>(agg1, W2, g, NN, HD, OD);
    hipMemsetAsync(agg2, 0, (size_t)NN * OD * sizeof(float), stream);
    scatter_k<OD><<<(NE * (OD / 4) + 255) / 256, 256, 0, stream>>>(g, src, dst, dinv, agg2);
    post_k<OD, false><<<(NN * (OD / 4) + 255) / 256, 256, 0, stream>>>(agg2, g, dinv, b2, out);
}

// Round 5
// 404.719 us; speedup vs baseline: 5.5701x; 5.5701x over previous
//
#include <hip/hip_runtime.h>

#define NN 50000
#define NE 800000
#define IND 256
#define HD 128
#define OD 64

// ---------- degree / normalization ----------

__global__ void deg_count_i(const int* __restrict__ dst, int* __restrict__ deg) {
    int e = blockIdx.x * 256 + threadIdx.x;
    if (e < NE) atomicAdd(&deg[dst[e]], 1);
}

__global__ void dinv_k(const int* __restrict__ deg, float* __restrict__ dinv) {
    int i = blockIdx.x * 256 + threadIdx.x;
    if (i < NN) dinv[i] = rsqrtf((float)deg[i] + 1.0f);   // +1 self-loop; always >= 1
}

// Exclusive prefix sum of deg[0..NN) -> off[0..NN], single workgroup, shfl-based.
__launch_bounds__(1024)
__global__ void scan_k(const int* __restrict__ deg, int* __restrict__ off) {
    __shared__ int wsum[16];
    __shared__ int carry_s;
    const int tid = threadIdx.x;
    const int lane = tid & 63, wv = tid >> 6;
    if (tid == 0) carry_s = 0;
    __syncthreads();
    for (int base = 0; base < NN; base += 1024) {
        int idx = base + tid;
        int v = (idx < NN) ? deg[idx] : 0;
        int inc = v;
#pragma unroll
        for (int ofs = 1; ofs < 64; ofs <<= 1) {
            int t = __shfl_up(inc, ofs, 64);
            if (lane >= ofs) inc += t;
        }
        if (lane == 63) wsum[wv] = inc;
        __syncthreads();
        int wprefix = 0;
#pragma unroll
        for (int w = 0; w < 16; ++w) wprefix += (w < wv) ? wsum[w] : 0;
        int c = carry_s;
        __syncthreads();   // everyone has read carry_s before it's rewritten
        if (idx < NN) off[idx] = c + wprefix + inc - v;   // exclusive
        if (tid == 1023) carry_s = c + wprefix + inc;     // chunk total
        __syncthreads();
    }
    if (tid == 0) off[NN] = carry_s;
}

__global__ void fill_k(const int* __restrict__ src, const int* __restrict__ dst,
                       const int* __restrict__ off, int* __restrict__ cursor,
                       int* __restrict__ csr_src) {
    int e = blockIdx.x * 256 + threadIdx.x;
    if (e < NE) {
        int d = dst[e];
        int p = atomicAdd(&cursor[d], 1);
        csr_src[off[d] + p] = src[e];
    }
}

// ---------- GEMM with per-row scale epilogue: C[m,:] = (A@B)[m,:] * rs[m] ----------

template<int BM, int BN, int BK, int TM, int TN>
__launch_bounds__(256)
__global__ void gemm_k(const float* __restrict__ A, const float* __restrict__ B,
                       const float* __restrict__ rs, float* __restrict__ C,
                       int M, int K, int N) {
    static_assert(TM == 4, "A-fragment read assumes TM==4");
    __shared__ float As[BK][BM + 4];
    __shared__ float Bs[BK][BN];
    const int tid = threadIdx.x;
    const int tx = tid % (BN / TN);
    const int ty = tid / (BN / TN);
    const int m0 = blockIdx.x * BM;

    float acc[TM][TN];
#pragma unroll
    for (int r = 0; r < TM; ++r)
#pragma unroll
        for (int c = 0; c < TN; ++c) acc[r][c] = 0.0f;

    for (int k0 = 0; k0 < K; k0 += BK) {
#pragma unroll
        for (int idx = tid; idx < BM * BK / 4; idx += 256) {
            int m  = idx / (BK / 4);
            int kq = (idx % (BK / 4)) * 4;
            float4 v = make_float4(0.f, 0.f, 0.f, 0.f);
            if (m0 + m < M)
                v = *(const float4*)&A[(long)(m0 + m) * K + k0 + kq];
            As[kq + 0][m] = v.x;
            As[kq + 1][m] = v.y;
            As[kq + 2][m] = v.z;
            As[kq + 3][m] = v.w;
        }
#pragma unroll
        for (int idx = tid; idx < BK * BN / 4; idx += 256) {
            int k  = idx / (BN / 4);
            int nq = (idx % (BN / 4)) * 4;
            *(float4*)&Bs[k][nq] = *(const float4*)&B[(long)(k0 + k) * N + nq];
        }
        __syncthreads();

#pragma unroll
        for (int kk = 0; kk < BK; ++kk) {
            float a[TM];
            *(float4*)a = *(const float4*)&As[kk][ty * TM];
            float b[TN];
#pragma unroll
            for (int c = 0; c < TN; c += 4) {
                float4 bv = *(const float4*)&Bs[kk][tx * TN + c];
                b[c + 0] = bv.x; b[c + 1] = bv.y; b[c + 2] = bv.z; b[c + 3] = bv.w;
            }
#pragma unroll
            for (int r = 0; r < TM; ++r)
#pragma unroll
                for (int c = 0; c < TN; ++c)
                    acc[r][c] = fmaf(a[r], b[c], acc[r][c]);
        }
        __syncthreads();
    }

#pragma unroll
    for (int r = 0; r < TM; ++r) {
        int row = m0 + ty * TM + r;
        if (row < M) {
            float sc = rs[row];
#pragma unroll
            for (int c = 0; c < TN; c += 4) {
                float4 o = make_float4(acc[r][c] * sc, acc[r][c + 1] * sc,
                                       acc[r][c + 2] * sc, acc[r][c + 3] * sc);
                *(float4*)&C[(long)row * N + tx * TN + c] = o;
            }
        }
    }
}

// ---------- pull-mode aggregation: one wave per dst node, zero atomics ----------
// out[d,:] = [relu]( (feat_s[d,:] + sum_{e in CSR[d]} feat_s[src[e],:]) * dinv[d] + bias )
template<int F, bool RELU>
__launch_bounds__(256)
__global__ void gather_k(const float* __restrict__ feat_s, const int* __restrict__ csr_src,
                         const int* __restrict__ off, const float* __restrict__ dinv,
                         const float* __restrict__ bias, float* __restrict__ out) {
    const int w = (int)((blockIdx.x * 256 + threadIdx.x) >> 6);
    const int lane = threadIdx.x & 63;
    if (w >= NN) return;
    const int o0 = off[w], o1 = off[w + 1];

    if constexpr (F == 128) {
        float2 sv = *(const float2*)&feat_s[(size_t)w * F + lane * 2];
        float a0 = sv.x, a1 = sv.y;
        int i = o0;
        for (; i + 1 < o1; i += 2) {
            int s0 = csr_src[i], s1 = csr_src[i + 1];
            float2 v0 = *(const float2*)&feat_s[(size_t)s0 * F + lane * 2];
            float2 v1 = *(const float2*)&feat_s[(size_t)s1 * F + lane * 2];
            a0 += v0.x + v1.x;
            a1 += v0.y + v1.y;
        }
        if (i < o1) {
            int s0 = csr_src[i];
            float2 v0 = *(const float2*)&feat_s[(size_t)s0 * F + lane * 2];
            a0 += v0.x; a1 += v0.y;
        }
        float dd = dinv[w];
        float r0 = fmaf(a0, dd, bias[lane * 2 + 0]);
        float r1 = fmaf(a1, dd, bias[lane * 2 + 1]);
        if (RELU) { r0 = fmaxf(r0, 0.f); r1 = fmaxf(r1, 0.f); }
        *(float2*)&out[(size_t)w * F + lane * 2] = make_float2(r0, r1);
    } else {
        float a0 = feat_s[(size_t)w * F + lane];
        int i = o0;
        for (; i + 1 < o1; i += 2) {
            int s0 = csr_src[i], s1 = csr_src[i + 1];
            a0 += feat_s[(size_t)s0 * F + lane] + feat_s[(size_t)s1 * F + lane];
        }
        if (i < o1) a0 += feat_s[(size_t)csr_src[i] * F + lane];
        float r0 = fmaf(a0, dinv[w], bias[lane]);
        if (RELU) r0 = fmaxf(r0, 0.f);
        out[(size_t)w * F + lane] = r0;
    }
}

extern "C" void kernel_launch(void* const* d_in, const int* in_sizes, int n_in,
                              void* d_out, int out_size, void* d_ws, size_t ws_size,
                              hipStream_t stream) {
    const float* x   = (const float*)d_in[0];
    const int*   src = (const int*)d_in[1];            // edge_index[0]
    const int*   dst = ((const int*)d_in[1]) + NE;     // edge_index[1]
    const float* W1  = (const float*)d_in[2];
    const float* b1  = (const float*)d_in[3];
    const float* W2  = (const float*)d_in[4];
    const float* b2  = (const float*)d_in[5];
    float* out = (float*)d_out;

    // workspace carve-up (floats then ints); gs aliases h1s (dead after gather1).
    // Total: (50048 + 2*NN*HD)*4B + ~950148*4B  ≈ 55 MB.
    float* dinv = (float*)d_ws;                         // 50048
    float* h1s  = dinv + 50048;                         // NN*HD  (scaled gemm1 out; later gs)
    float* h    = h1s + (size_t)NN * HD;                // NN*HD  (layer-1 output)
    float* gs   = h1s;                                  // NN*OD aliases h1s
    int* deg_i  = (int*)(h + (size_t)NN * HD);          // 50048
    int* off    = deg_i + 50048;                        // 50052 (need NN+1)
    int* cursor = off + 50052;                          // 50048
    int* csr    = cursor + 50048;                       // NE

    // CSR build (graph fixed per call; reused by both layers)
    hipMemsetAsync(deg_i, 0, 50048 * sizeof(int), stream);
    hipMemsetAsync(cursor, 0, 50048 * sizeof(int), stream);
    deg_count_i<<<(NE + 255) / 256, 256, 0, stream>>>(dst, deg_i);
    dinv_k<<<(NN + 255) / 256, 256, 0, stream>>>(deg_i, dinv);
    scan_k<<<1, 1024, 0, stream>>>(deg_i, off);
    fill_k<<<(NE + 255) / 256, 256, 0, stream>>>(src, dst, off, cursor, csr);

    // layer 1: h1s = (x @ W1) * dinv[row]; h = relu(gather(h1s)*dinv + b1)
    gemm_k<64, 128, 32, 4, 8><<<(NN + 63) / 64, 256, 0, stream>>>(x, W1, dinv, h1s, NN, IND, HD);
    gather_k<HD, true><<<(NN + 3) / 4, 256, 0, stream>>>(h1s, csr, off, dinv, b1, h);

    // layer 2: gs = (h @ W2) * dinv[row]; out = gather(gs)*dinv + b2
    gemm_k<64, 64, 32, 4, 4><<<(NN + 63) / 64, 256, 0, stream>>>(h, W2, dinv, gs, NN, HD, OD);
    gather_k<OD, false><<<(NN + 3) / 4, 256, 0, stream>>>(gs, csr, off, dinv, b2, out);
}

// Round 6
// 381.017 us; speedup vs baseline: 5.9166x; 1.0622x over previous
//
#include <hip/hip_runtime.h>

#define NN 50000
#define NE 800000
#define IND 256
#define HD 128
#define OD 64
#define SCAN_NBLK ((NN + 1023) / 1024)   // 49

// ---------- degree / normalization ----------

__global__ void deg_count_i(const int* __restrict__ dst, int* __restrict__ deg) {
    int e = blockIdx.x * 256 + threadIdx.x;
    if (e < NE) atomicAdd(&deg[dst[e]], 1);
}

__global__ void dinv_k(const int* __restrict__ deg, float* __restrict__ dinv) {
    int i = blockIdx.x * 256 + threadIdx.x;
    if (i < NN) dinv[i] = rsqrtf((float)deg[i] + 1.0f);   // +1 self-loop; always >= 1
}

// ---------- multi-block exclusive scan: deg -> off ----------

__launch_bounds__(1024)
__global__ void scan1_k(const int* __restrict__ deg, int* __restrict__ off,
                        int* __restrict__ btot) {
    __shared__ int wsum[16];
    const int tid = threadIdx.x, lane = tid & 63, wv = tid >> 6;
    const int idx = blockIdx.x * 1024 + tid;
    int v = (idx < NN) ? deg[idx] : 0;
    int inc = v;
#pragma unroll
    for (int ofs = 1; ofs < 64; ofs <<= 1) {
        int t = __shfl_up(inc, ofs, 64);
        if (lane >= ofs) inc += t;
    }
    if (lane == 63) wsum[wv] = inc;
    __syncthreads();
    int wprefix = 0;
#pragma unroll
    for (int w = 0; w < 16; ++w) wprefix += (w < wv) ? wsum[w] : 0;
    if (idx < NN) off[idx] = wprefix + inc - v;          // block-local exclusive
    if (tid == 1023) btot[blockIdx.x] = wprefix + inc;   // block total
}

__launch_bounds__(64)
__global__ void scan2_k(int* __restrict__ btot, int* __restrict__ off) {
    const int lane = threadIdx.x;   // single wave; SCAN_NBLK <= 64
    int v = (lane < SCAN_NBLK) ? btot[lane] : 0;
    int inc = v;
#pragma unroll
    for (int ofs = 1; ofs < 64; ofs <<= 1) {
        int t = __shfl_up(inc, ofs, 64);
        if (lane >= ofs) inc += t;
    }
    if (lane < SCAN_NBLK) btot[lane] = inc - v;          // exclusive block offsets
    if (lane == 63) off[NN] = inc;                       // grand total (= NE)
}

__launch_bounds__(1024)
__global__ void scan3_k(int* __restrict__ off, const int* __restrict__ btot) {
    const int idx = blockIdx.x * 1024 + threadIdx.x;
    if (idx < NN) off[idx] += btot[blockIdx.x];
}

__global__ void fill_k(const int* __restrict__ src, const int* __restrict__ dst,
                       const int* __restrict__ off, int* __restrict__ cursor,
                       int* __restrict__ csr_src) {
    int e = blockIdx.x * 256 + threadIdx.x;
    if (e < NE) {
        int d = dst[e];
        int p = atomicAdd(&cursor[d], 1);
        csr_src[off[d] + p] = src[e];
    }
}

// ---------- GEMM, conflict-free fragment map ----------
// 256 threads = 4 waves. Wave wv owns rows [wv*TM, wv*TM+TM); lane owns cols
// [lane*TN, lane*TN+TN).  Requires BM == 4*TM, BN == 64*TN, TM % 4 == 0.
// Bs reads: lane*TN floats -> stride-1 512B/wave (2-way, free).
// As reads: wave-uniform address -> broadcast (free).
// C[m,:] = (A@B)[m,:] * rs[m]
template<int BM, int BN, int BK, int TM, int TN>
__launch_bounds__(256)
__global__ void gemm_k(const float* __restrict__ A, const float* __restrict__ B,
                       const float* __restrict__ rs, float* __restrict__ C,
                       int M, int K, int N) {
    static_assert(BM == 4 * TM && BN == 64 * TN && TM % 4 == 0, "bad tile");
    static_assert((BM + 4) % 4 == 0, "As row must stay 16B aligned");
    __shared__ float As[BK][BM + 4];   // transposed; +4 keeps rows 16B aligned
    __shared__ float Bs[BK][BN];
    const int tid  = threadIdx.x;
    const int lane = tid & 63;
    const int wv   = tid >> 6;
    const int m0   = blockIdx.x * BM;

    float acc[TM][TN];
#pragma unroll
    for (int r = 0; r < TM; ++r)
#pragma unroll
        for (int c = 0; c < TN; ++c) acc[r][c] = 0.0f;

    for (int k0 = 0; k0 < K; k0 += BK) {
        // stage A (BM x BK) transposed into As[k][m]
#pragma unroll
        for (int idx = tid; idx < BM * BK / 4; idx += 256) {
            int m  = idx / (BK / 4);
            int kq = (idx % (BK / 4)) * 4;
            float4 v = make_float4(0.f, 0.f, 0.f, 0.f);
            if (m0 + m < M)
                v = *(const float4*)&A[(long)(m0 + m) * K + k0 + kq];
            As[kq + 0][m] = v.x;
            As[kq + 1][m] = v.y;
            As[kq + 2][m] = v.z;
            As[kq + 3][m] = v.w;
        }
        // stage B (BK x BN) contiguous
#pragma unroll
        for (int idx = tid; idx < BK * BN / 4; idx += 256) {
            int k  = idx / (BN / 4);
            int nq = (idx % (BN / 4)) * 4;
            *(float4*)&Bs[k][nq] = *(const float4*)&B[(long)(k0 + k) * N + nq];
        }
        __syncthreads();

#pragma unroll
        for (int kk = 0; kk < BK; ++kk) {
            float a[TM];
#pragma unroll
            for (int j = 0; j < TM; j += 4)
                *(float4*)&a[j] = *(const float4*)&As[kk][wv * TM + j];  // broadcast
            float b[TN];
            if constexpr (TN == 2) {
                float2 bv = *(const float2*)&Bs[kk][lane * 2];
                b[0] = bv.x; b[1] = bv.y;
            } else {
                b[0] = Bs[kk][lane];
            }
#pragma unroll
            for (int r = 0; r < TM; ++r)
#pragma unroll
                for (int c = 0; c < TN; ++c)
                    acc[r][c] = fmaf(a[r], b[c], acc[r][c]);
        }
        __syncthreads();
    }

#pragma unroll
    for (int r = 0; r < TM; ++r) {
        int row = m0 + wv * TM + r;
        if (row < M) {
            float sc = rs[row];
            if constexpr (TN == 2) {
                *(float2*)&C[(long)row * N + lane * 2] =
                    make_float2(acc[r][0] * sc, acc[r][1] * sc);
            } else {
                C[(long)row * N + lane] = acc[r][0] * sc;
            }
        }
    }
}

// ---------- pull-mode aggregation: one wave per dst node, zero atomics ----------
// out[d,:] = [relu]( (feat_s[d,:] + sum_{e in CSR[d]} feat_s[src[e],:]) * dinv[d] + bias )
template<int F, bool RELU>
__launch_bounds__(256)
__global__ void gather_k(const float* __restrict__ feat_s, const int* __restrict__ csr_src,
                         const int* __restrict__ off, const float* __restrict__ dinv,
                         const float* __restrict__ bias, float* __restrict__ out) {
    const int w = (int)((blockIdx.x * 256 + threadIdx.x) >> 6);
    const int lane = threadIdx.x & 63;
    if (w >= NN) return;
    const int o0 = off[w], o1 = off[w + 1];

    if constexpr (F == 128) {
        float2 sv = *(const float2*)&feat_s[(size_t)w * F + lane * 2];
        float a0 = sv.x, a1 = sv.y;
        int i = o0;
        for (; i + 1 < o1; i += 2) {
            int s0 = csr_src[i], s1 = csr_src[i + 1];
            float2 v0 = *(const float2*)&feat_s[(size_t)s0 * F + lane * 2];
            float2 v1 = *(const float2*)&feat_s[(size_t)s1 * F + lane * 2];
            a0 += v0.x + v1.x;
            a1 += v0.y + v1.y;
        }
        if (i < o1) {
            int s0 = csr_src[i];
            float2 v0 = *(const float2*)&feat_s[(size_t)s0 * F + lane * 2];
            a0 += v0.x; a1 += v0.y;
        }
        float dd = dinv[w];
        float r0 = fmaf(a0, dd, bias[lane * 2 + 0]);
        float r1 = fmaf(a1, dd, bias[lane * 2 + 1]);
        if (RELU) { r0 = fmaxf(r0, 0.f); r1 = fmaxf(r1, 0.f); }
        *(float2*)&out[(size_t)w * F + lane * 2] = make_float2(r0, r1);
    } else {
        float a0 = feat_s[(size_t)w * F + lane];
        int i = o0;
        for (; i + 1 < o1; i += 2) {
            int s0 = csr_src[i], s1 = csr_src[i + 1];
            a0 += feat_s[(size_t)s0 * F + lane] + feat_s[(size_t)s1 * F + lane];
        }
        if (i < o1) a0 += feat_s[(size_t)csr_src[i] * F + lane];
        float r0 = fmaf(a0, dinv[w], bias[lane]);
        if (RELU) r0 = fmaxf(r0, 0.f);
        out[(size_t)w * F + lane] = r0;
    }
}

extern "C" void kernel_launch(void* const* d_in, const int* in_sizes, int n_in,
                              void* d_out, int out_size, void* d_ws, size_t ws_size,
                              hipStream_t stream) {
    const float* x   = (const float*)d_in[0];
    const int*   src = (const int*)d_in[1];            // edge_index[0]
    const int*   dst = ((const int*)d_in[1]) + NE;     // edge_index[1]
    const float* W1  = (const float*)d_in[2];
    const float* b1  = (const float*)d_in[3];
    const float* W2  = (const float*)d_in[4];
    const float* b2  = (const float*)d_in[5];
    float* out = (float*)d_out;

    // workspace carve-up (floats then ints); gs aliases h1s (dead after gather1).
    float* dinv = (float*)d_ws;                         // 50048
    float* h1s  = dinv + 50048;                         // NN*HD  (scaled gemm1 out; later gs)
    float* h    = h1s + (size_t)NN * HD;                // NN*HD  (layer-1 output)
    float* gs   = h1s;                                  // NN*OD aliases h1s
    int* deg_i  = (int*)(h + (size_t)NN * HD);          // 50048
    int* off    = deg_i + 50048;                        // 50052 (need NN+1)
    int* cursor = off + 50052;                          // 50048
    int* btot   = cursor + 50048;                       // 64
    int* csr    = btot + 64;                            // NE

    // CSR build (graph fixed per call; reused by both layers)
    hipMemsetAsync(deg_i, 0, 50048 * sizeof(int), stream);
    hipMemsetAsync(cursor, 0, 50048 * sizeof(int), stream);
    deg_count_i<<<(NE + 255) / 256, 256, 0, stream>>>(dst, deg_i);
    dinv_k<<<(NN + 255) / 256, 256, 0, stream>>>(deg_i, dinv);
    scan1_k<<<SCAN_NBLK, 1024, 0, stream>>>(deg_i, off, btot);
    scan2_k<<<1, 64, 0, stream>>>(btot, off);
    scan3_k<<<SCAN_NBLK, 1024, 0, stream>>>(off, btot);
    fill_k<<<(NE + 255) / 256, 256, 0, stream>>>(src, dst, off, cursor, csr);

    // layer 1: h1s = (x @ W1) * dinv[row]; h = relu(gather(h1s)*dinv + b1)
    gemm_k<32, 128, 32, 8, 2><<<(NN + 31) / 32, 256, 0, stream>>>(x, W1, dinv, h1s, NN, IND, HD);
    gather_k<HD, true><<<(NN + 3) / 4, 256, 0, stream>>>(h1s, csr, off, dinv, b1, h);

    // layer 2: gs = (h @ W2) * dinv[row]; out = gather(gs)*dinv + b2
    gemm_k<32, 64, 32, 8, 1><<<(NN + 31) / 32, 256, 0, stream>>>(h, W2, dinv, gs, NN, HD, OD);
    gather_k<OD, false><<<(NN + 3) / 4, 256, 0, stream>>>(gs, csr, off, dinv, b2, out);
}

// Round 7
// 306.757 us; speedup vs baseline: 7.3489x; 1.2421x over previous
//
#include <hip/hip_runtime.h>

#define NN 50000
#define NE 800000
#define IND 256
#define HD 128
#define OD 64
#define SCAN_NBLK ((NN + 1023) / 1024)   // 49

typedef __attribute__((ext_vector_type(8))) short short8;
typedef __attribute__((ext_vector_type(4))) float f32x4;

static __device__ __forceinline__ ushort f2bf(float f) {
    uint u = __float_as_uint(f);
    u += 0x7fff + ((u >> 16) & 1);        // round-to-nearest-even
    return (ushort)(u >> 16);
}
static __device__ __forceinline__ float bf2f(ushort h) {
    return __uint_as_float(((uint)h) << 16);
}

// ---------- degree / normalization ----------

__global__ void deg_count_i(const int* __restrict__ dst, int* __restrict__ deg) {
    int e = blockIdx.x * 256 + threadIdx.x;
    if (e < NE) atomicAdd(&deg[dst[e]], 1);
}

__global__ void dinv_k(const int* __restrict__ deg, float* __restrict__ dinv) {
    int i = blockIdx.x * 256 + threadIdx.x;
    if (i < NN) dinv[i] = rsqrtf((float)deg[i] + 1.0f);   // +1 self-loop
}

// ---------- multi-block exclusive scan: deg -> off ----------

__launch_bounds__(1024)
__global__ void scan1_k(const int* __restrict__ deg, int* __restrict__ off,
                        int* __restrict__ btot) {
    __shared__ int wsum[16];
    const int tid = threadIdx.x, lane = tid & 63, wv = tid >> 6;
    const int idx = blockIdx.x * 1024 + tid;
    int v = (idx < NN) ? deg[idx] : 0;
    int inc = v;
#pragma unroll
    for (int ofs = 1; ofs < 64; ofs <<= 1) {
        int t = __shfl_up(inc, ofs, 64);
        if (lane >= ofs) inc += t;
    }
    if (lane == 63) wsum[wv] = inc;
    __syncthreads();
    int wprefix = 0;
#pragma unroll
    for (int w = 0; w < 16; ++w) wprefix += (w < wv) ? wsum[w] : 0;
    if (idx < NN) off[idx] = wprefix + inc - v;
    if (tid == 1023) btot[blockIdx.x] = wprefix + inc;
}

__launch_bounds__(64)
__global__ void scan2_k(int* __restrict__ btot, int* __restrict__ off) {
    const int lane = threadIdx.x;
    int v = (lane < SCAN_NBLK) ? btot[lane] : 0;
    int inc = v;
#pragma unroll
    for (int ofs = 1; ofs < 64; ofs <<= 1) {
        int t = __shfl_up(inc, ofs, 64);
        if (lane >= ofs) inc += t;
    }
    if (lane < SCAN_NBLK) btot[lane] = inc - v;
    if (lane == 63) off[NN] = inc;
}

__launch_bounds__(1024)
__global__ void scan3_k(int* __restrict__ off, const int* __restrict__ btot) {
    const int idx = blockIdx.x * 1024 + threadIdx.x;
    if (idx < NN) off[idx] += btot[blockIdx.x];
}

__global__ void fill_k(const int* __restrict__ src, const int* __restrict__ dst,
                       const int* __restrict__ off, int* __restrict__ cursor,
                       int* __restrict__ csr_src) {
    int e = blockIdx.x * 256 + threadIdx.x;
    if (e < NE) {
        int d = dst[e];
        int p = atomicAdd(&cursor[d], 1);
        csr_src[off[d] + p] = src[e];
    }
}

// ---------- W prep: f32 W[K][N] -> fragment-ordered bf16 pairs (u32) ----------
// u32 index i = ((c8*NT + nt)*64 + lane)*4 + jp, holding W[k][n],W[k+1][n] with
// k = c8*32 + (lane>>4)*8 + 2*jp, n = nt*16 + (lane&15).  Region (c8,nt) = 1KB,
// laid out so global_load_lds(lane*16) lands fragments linearly in LDS.
template<int N, int K>
__global__ void prep_w_k(const float* __restrict__ W, uint* __restrict__ Wp) {
    constexpr int NT = N / 16;
    constexpr int TOT = (K / 32) * NT * 256;
    int i = blockIdx.x * 256 + threadIdx.x;
    if (i >= TOT) return;
    int region = i >> 8;
    int lane = (i >> 2) & 63;
    int jp = i & 3;
    int c8 = region / NT, nt = region % NT;
    int k = c8 * 32 + (lane >> 4) * 8 + jp * 2;
    int n = nt * 16 + (lane & 15);
    Wp[i] = (uint)f2bf(W[k * N + n]) | ((uint)f2bf(W[(k + 1) * N + n]) << 16);
}

// ---------- MFMA GEMM: Cbf[M][N] = bf16( (A @ W) * rs[row] ) ----------
// 4 waves x 16 rows = 64 rows/block.  W staged via global_load_lds from the
// fragment-ordered Wp (zero LDS write conflicts, linear ds_read_b128).
template<int N, int K, bool CONVA>
__launch_bounds__(256)
__global__ void mfma_gemm_k(const void* __restrict__ Ap, const uint* __restrict__ Wp,
                            const float* __restrict__ rs, ushort* __restrict__ Cbf,
                            int M) {
    constexpr int NT = N / 16;            // 16-col tiles
    constexpr int KH = K / 128;           // 128-wide K halves
    constexpr int NREG = 4 * NT;          // regions per half
    __shared__ uint bsl[NREG * 256];      // NREG KiB
    const int tid = threadIdx.x, lane = tid & 63, wv = tid >> 6;
    const int row = blockIdx.x * 64 + wv * 16 + (lane & 15);
    const int rowc = min(row, M - 1);
    const int kl = (lane >> 4) * 8;

    f32x4 acc[NT];
#pragma unroll
    for (int t = 0; t < NT; ++t) acc[t] = (f32x4){0.f, 0.f, 0.f, 0.f};

    for (int h = 0; h < KH; ++h) {
        if (h) __syncthreads();           // protect bsl reuse
#pragma unroll
        for (int rg = wv; rg < NREG; rg += 4)
            __builtin_amdgcn_global_load_lds(
                (const uint __attribute__((address_space(1)))*)(Wp + (size_t)(h * NREG + rg) * 256 + lane * 4),
                (uint __attribute__((address_space(3)))*)&bsl[rg * 256], 16, 0, 0);
        __syncthreads();                  // vmcnt(0) drain before use
#pragma unroll
        for (int c = 0; c < 4; ++c) {
            const int k0 = h * 128 + c * 32;
            short8 af;
            if constexpr (CONVA) {
                const float* A = (const float*)Ap;
                f32x4 lo = *(const f32x4*)&A[(size_t)rowc * K + k0 + kl];
                f32x4 hi = *(const f32x4*)&A[(size_t)rowc * K + k0 + kl + 4];
                af[0] = (short)f2bf(lo.x); af[1] = (short)f2bf(lo.y);
                af[2] = (short)f2bf(lo.z); af[3] = (short)f2bf(lo.w);
                af[4] = (short)f2bf(hi.x); af[5] = (short)f2bf(hi.y);
                af[6] = (short)f2bf(hi.z); af[7] = (short)f2bf(hi.w);
            } else {
                const ushort* A = (const ushort*)Ap;
                af = *(const short8*)&A[(size_t)rowc * K + k0 + kl];
            }
#pragma unroll
            for (int t = 0; t < NT; ++t) {
                short8 bf = *(const short8*)&bsl[(c * NT + t) * 256 + lane * 4];
                acc[t] = __builtin_amdgcn_mfma_f32_16x16x32_bf16(af, bf, acc[t], 0, 0, 0);
            }
        }
    }
    const int crow = blockIdx.x * 64 + wv * 16 + (lane >> 4) * 4;
#pragma unroll
    for (int t = 0; t < NT; ++t) {
        int col = t * 16 + (lane & 15);
#pragma unroll
        for (int r = 0; r < 4; ++r)
            if (crow + r < M)
                Cbf[(size_t)(crow + r) * N + col] = f2bf(acc[t][r] * rs[crow + r]);
    }
}

// ---------- pull-mode gathers (bf16 tables, f32 accumulation) ----------

__launch_bounds__(256)
__global__ void gather1_k(const ushort* __restrict__ feat, const int* __restrict__ csr,
                          const int* __restrict__ off, const float* __restrict__ dinv,
                          const float* __restrict__ bias, ushort* __restrict__ outbf) {
    const int w = (int)((blockIdx.x * 256 + threadIdx.x) >> 6);
    const int lane = threadIdx.x & 63;
    if (w >= NN) return;
    const int o0 = off[w], o1 = off[w + 1];
    const int c2 = lane * 2;
    uint sv = *(const uint*)&feat[(size_t)w * HD + c2];
    float a0 = bf2f((ushort)sv), a1 = bf2f((ushort)(sv >> 16));
    int i = o0;
    for (; i + 1 < o1; i += 2) {
        int s0 = csr[i], s1 = csr[i + 1];
        uint v0 = *(const uint*)&feat[(size_t)s0 * HD + c2];
        uint v1 = *(const uint*)&feat[(size_t)s1 * HD + c2];
        a0 += bf2f((ushort)v0) + bf2f((ushort)v1);
        a1 += bf2f((ushort)(v0 >> 16)) + bf2f((ushort)(v1 >> 16));
    }
    if (i < o1) {
        uint v0 = *(const uint*)&feat[(size_t)csr[i] * HD + c2];
        a0 += bf2f((ushort)v0); a1 += bf2f((ushort)(v0 >> 16));
    }
    float dd = dinv[w];
    float r0 = fmaxf(fmaf(a0, dd, bias[c2 + 0]), 0.f);
    float r1 = fmaxf(fmaf(a1, dd, bias[c2 + 1]), 0.f);
    *(uint*)&outbf[(size_t)w * HD + c2] = (uint)f2bf(r0) | ((uint)f2bf(r1) << 16);
}

__launch_bounds__(256)
__global__ void gather2_k(const ushort* __restrict__ feat, const int* __restrict__ csr,
                          const int* __restrict__ off, const float* __restrict__ dinv,
                          const float* __restrict__ bias, float* __restrict__ out) {
    const int w = (int)((blockIdx.x * 256 + threadIdx.x) >> 6);
    const int lane = threadIdx.x & 63;
    if (w >= NN) return;
    const int o0 = off[w], o1 = off[w + 1];
    float a = bf2f(feat[(size_t)w * OD + lane]);
    int i = o0;
    for (; i + 1 < o1; i += 2) {
        int s0 = csr[i], s1 = csr[i + 1];
        a += bf2f(feat[(size_t)s0 * OD + lane]) + bf2f(feat[(size_t)s1 * OD + lane]);
    }
    if (i < o1) a += bf2f(feat[(size_t)csr[i] * OD + lane]);
    out[(size_t)w * OD + lane] = fmaf(a, dinv[w], bias[lane]);
}

extern "C" void kernel_launch(void* const* d_in, const int* in_sizes, int n_in,
                              void* d_out, int out_size, void* d_ws, size_t ws_size,
                              hipStream_t stream) {
    const float* x   = (const float*)d_in[0];
    const int*   src = (const int*)d_in[1];
    const int*   dst = ((const int*)d_in[1]) + NE;
    const float* W1  = (const float*)d_in[2];
    const float* b1  = (const float*)d_in[3];
    const float* W2  = (const float*)d_in[4];
    const float* b2  = (const float*)d_in[5];
    float* out = (float*)d_out;

    // workspace carve-up (~36 MB)
    float*  dinv   = (float*)d_ws;                       // 50048 f32
    uint*   W1p    = (uint*)(dinv + 50048);              // 16384 u32 (64 KB)
    uint*   W2p    = W1p + 16384;                        // 4096 u32 (16 KB)
    ushort* h1s_bf = (ushort*)(W2p + 4096);              // NN*HD bf16
    ushort* h_bf   = h1s_bf + (size_t)NN * HD;           // NN*HD bf16
    ushort* gs_bf  = h_bf + (size_t)NN * HD;             // NN*OD bf16
    int* deg_i  = (int*)(gs_bf + (size_t)NN * OD);       // 50048
    int* off    = deg_i + 50048;                         // 50052
    int* cursor = off + 50052;                           // 50048
    int* btot   = cursor + 50048;                        // 64
    int* csr    = btot + 64;                             // NE

    // CSR build + normalization
    hipMemsetAsync(deg_i, 0, 50048 * sizeof(int), stream);
    hipMemsetAsync(cursor, 0, 50048 * sizeof(int), stream);
    deg_count_i<<<(NE + 255) / 256, 256, 0, stream>>>(dst, deg_i);
    dinv_k<<<(NN + 255) / 256, 256, 0, stream>>>(deg_i, dinv);
    scan1_k<<<SCAN_NBLK, 1024, 0, stream>>>(deg_i, off, btot);
    scan2_k<<<1, 64, 0, stream>>>(btot, off);
    scan3_k<<<SCAN_NBLK, 1024, 0, stream>>>(off, btot);
    fill_k<<<(NE + 255) / 256, 256, 0, stream>>>(src, dst, off, cursor, csr);

    // weight prep (fragment-ordered bf16)
    prep_w_k<HD, IND><<<64, 256, 0, stream>>>(W1, W1p);
    prep_w_k<OD, HD><<<16, 256, 0, stream>>>(W2, W2p);

    // layer 1
    mfma_gemm_k<HD, IND, true><<<(NN + 63) / 64, 256, 0, stream>>>(x, W1p, dinv, h1s_bf, NN);
    gather1_k<<<(NN + 3) / 4, 256, 0, stream>>>(h1s_bf, csr, off, dinv, b1, h_bf);

    // layer 2
    mfma_gemm_k<OD, HD, false><<<(NN + 63) / 64, 256, 0, stream>>>(h_bf, W2p, dinv, gs_bf, NN);
    gather2_k<<<(NN + 3) / 4, 256, 0, stream>>>(gs_bf, csr, off, dinv, b2, out);
}

// Round 10
// 273.086 us; speedup vs baseline: 8.2551x; 1.1233x over previous
//
#include <hip/hip_runtime.h>

#define NN 50000
#define NE 800000
#define IND 256
#define HD 128
#define OD 64
#define SCAN_NBLK ((NN + 1023) / 1024)   // 49

typedef __attribute__((ext_vector_type(8))) short short8;
typedef __attribute__((ext_vector_type(4))) float f32x4;
typedef __attribute__((ext_vector_type(4))) uint u32x4;

static __device__ __forceinline__ ushort f2bf(float f) {
    uint u = __float_as_uint(f);
    u += 0x7fff + ((u >> 16) & 1);        // round-to-nearest-even
    return (ushort)(u >> 16);
}
static __device__ __forceinline__ float bf2f(ushort h) {
    return __uint_as_float(((uint)h) << 16);
}

// ---------- degree / normalization ----------

__global__ void deg_count_i(const int* __restrict__ dst, int* __restrict__ deg) {
    int e = blockIdx.x * 256 + threadIdx.x;
    if (e < NE) atomicAdd(&deg[dst[e]], 1);
}

__global__ void dinv_k(const int* __restrict__ deg, float* __restrict__ dinv) {
    int i = blockIdx.x * 256 + threadIdx.x;
    if (i < NN) dinv[i] = rsqrtf((float)deg[i] + 1.0f);   // +1 self-loop
}

// ---------- multi-block exclusive scan: deg -> off ----------

__launch_bounds__(1024)
__global__ void scan1_k(const int* __restrict__ deg, int* __restrict__ off,
                        int* __restrict__ btot) {
    __shared__ int wsum[16];
    const int tid = threadIdx.x, lane = tid & 63, wv = tid >> 6;
    const int idx = blockIdx.x * 1024 + tid;
    int v = (idx < NN) ? deg[idx] : 0;
    int inc = v;
#pragma unroll
    for (int ofs = 1; ofs < 64; ofs <<= 1) {
        int t = __shfl_up(inc, ofs, 64);
        if (lane >= ofs) inc += t;
    }
    if (lane == 63) wsum[wv] = inc;
    __syncthreads();
    int wprefix = 0;
#pragma unroll
    for (int w = 0; w < 16; ++w) wprefix += (w < wv) ? wsum[w] : 0;
    if (idx < NN) off[idx] = wprefix + inc - v;
    if (tid == 1023) btot[blockIdx.x] = wprefix + inc;
}

__launch_bounds__(64)
__global__ void scan2_k(int* __restrict__ btot, int* __restrict__ off) {
    const int lane = threadIdx.x;
    int v = (lane < SCAN_NBLK) ? btot[lane] : 0;
    int inc = v;
#pragma unroll
    for (int ofs = 1; ofs < 64; ofs <<= 1) {
        int t = __shfl_up(inc, ofs, 64);
        if (lane >= ofs) inc += t;
    }
    if (lane < SCAN_NBLK) btot[lane] = inc - v;
    if (lane == 63) off[NN] = inc;
}

__launch_bounds__(1024)
__global__ void scan3_k(int* __restrict__ off, const int* __restrict__ btot) {
    const int idx = blockIdx.x * 1024 + threadIdx.x;
    if (idx < NN) off[idx] += btot[blockIdx.x];
}

__global__ void fill_k(const int* __restrict__ src, const int* __restrict__ dst,
                       const int* __restrict__ off, int* __restrict__ cursor,
                       int* __restrict__ csr_src) {
    int e = blockIdx.x * 256 + threadIdx.x;
    if (e < NE) {
        int d = dst[e];
        int p = atomicAdd(&cursor[d], 1);
        csr_src[off[d] + p] = src[e];
    }
}

// ---------- W prep: f32 W[K][N] -> fragment-ordered bf16 pairs (u32) ----------
template<int N, int K>
__global__ void prep_w_k(const float* __restrict__ W, uint* __restrict__ Wp) {
    constexpr int NT = N / 16;
    constexpr int TOT = (K / 32) * NT * 256;
    int i = blockIdx.x * 256 + threadIdx.x;
    if (i >= TOT) return;
    int region = i >> 8;
    int lane = (i >> 2) & 63;
    int jp = i & 3;
    int c8 = region / NT, nt = region % NT;
    int k = c8 * 32 + (lane >> 4) * 8 + jp * 2;
    int n = nt * 16 + (lane & 15);
    Wp[i] = (uint)f2bf(W[k * N + n]) | ((uint)f2bf(W[(k + 1) * N + n]) << 16);
}

// ---------- MFMA GEMM: Cbf[M][N] = bf16( (A @ W) * rs[row] ) ----------
template<int N, int K, bool CONVA>
__launch_bounds__(256)
__global__ void mfma_gemm_k(const void* __restrict__ Ap, const uint* __restrict__ Wp,
                            const float* __restrict__ rs, ushort* __restrict__ Cbf,
                            int M) {
    constexpr int NT = N / 16;
    constexpr int KH = K / 128;
    constexpr int NREG = 4 * NT;
    __shared__ uint bsl[NREG * 256];
    const int tid = threadIdx.x, lane = tid & 63, wv = tid >> 6;
    const int row = blockIdx.x * 64 + wv * 16 + (lane & 15);
    const int rowc = min(row, M - 1);
    const int kl = (lane >> 4) * 8;

    f32x4 acc[NT];
#pragma unroll
    for (int t = 0; t < NT; ++t) acc[t] = (f32x4){0.f, 0.f, 0.f, 0.f};

    for (int h = 0; h < KH; ++h) {
        if (h) __syncthreads();
#pragma unroll
        for (int rg = wv; rg < NREG; rg += 4)
            __builtin_amdgcn_global_load_lds(
                (const uint __attribute__((address_space(1)))*)(Wp + (size_t)(h * NREG + rg) * 256 + lane * 4),
                (uint __attribute__((address_space(3)))*)&bsl[rg * 256], 16, 0, 0);
        __syncthreads();
#pragma unroll
        for (int c = 0; c < 4; ++c) {
            const int k0 = h * 128 + c * 32;
            short8 af;
            if constexpr (CONVA) {
                const float* A = (const float*)Ap;
                f32x4 lo = *(const f32x4*)&A[(size_t)rowc * K + k0 + kl];
                f32x4 hi = *(const f32x4*)&A[(size_t)rowc * K + k0 + kl + 4];
                af[0] = (short)f2bf(lo.x); af[1] = (short)f2bf(lo.y);
                af[2] = (short)f2bf(lo.z); af[3] = (short)f2bf(lo.w);
                af[4] = (short)f2bf(hi.x); af[5] = (short)f2bf(hi.y);
                af[6] = (short)f2bf(hi.z); af[7] = (short)f2bf(hi.w);
            } else {
                const ushort* A = (const ushort*)Ap;
                af = *(const short8*)&A[(size_t)rowc * K + k0 + kl];
            }
#pragma unroll
            for (int t = 0; t < NT; ++t) {
                short8 bf = *(const short8*)&bsl[(c * NT + t) * 256 + lane * 4];
                acc[t] = __builtin_amdgcn_mfma_f32_16x16x32_bf16(af, bf, acc[t], 0, 0, 0);
            }
        }
    }
    const int crow = blockIdx.x * 64 + wv * 16 + (lane >> 4) * 4;
#pragma unroll
    for (int t = 0; t < NT; ++t) {
        int col = t * 16 + (lane & 15);
#pragma unroll
        for (int r = 0; r < 4; ++r)
            if (crow + r < M)
                Cbf[(size_t)(crow + r) * N + col] = f2bf(acc[t][r] * rs[crow + r]);
    }
}

// ---------- wide pull-mode gathers: multiple edges per wave-instruction ----------
// gather1 (HD=128): wave = 4 edge-groups x 16 col-lanes; 16B/lane row slices.
// Self row contributes ONLY in group 0 (R8 bug: all groups added it, then the
// cross-group reduction multiplied it).
__launch_bounds__(256)
__global__ void gather1_k(const ushort* __restrict__ feat, const int* __restrict__ csr,
                          const int* __restrict__ off, const float* __restrict__ dinv,
                          const float* __restrict__ bias, ushort* __restrict__ outbf) {
    const int w = (int)((blockIdx.x * 256 + threadIdx.x) >> 6);
    const int lane = threadIdx.x & 63;
    if (w >= NN) return;
    const int g = lane >> 4;          // edge group 0..3
    const int c = lane & 15;          // col chunk: cols c*8 .. c*8+7
    const int o0 = off[w], o1 = off[w + 1];

    float a[8];
    if (g == 0) {   // self row, counted exactly once
        u32x4 sv = *(const u32x4*)&feat[(size_t)w * HD + c * 8];
#pragma unroll
        for (int j = 0; j < 4; ++j) {
            a[2 * j]     = bf2f((ushort)sv[j]);
            a[2 * j + 1] = bf2f((ushort)(sv[j] >> 16));
        }
    } else {
#pragma unroll
        for (int j = 0; j < 8; ++j) a[j] = 0.f;
    }
    for (int i = o0; i < o1; i += 4) {
        int idx = i + g;
        if (idx < o1) {
            int s = csr[idx];
            u32x4 v = *(const u32x4*)&feat[(size_t)s * HD + c * 8];
#pragma unroll
            for (int j = 0; j < 4; ++j) {
                a[2 * j]     += bf2f((ushort)v[j]);
                a[2 * j + 1] += bf2f((ushort)(v[j] >> 16));
            }
        }
    }
    // sum the 4 edge-groups (lane bits 4-5)
#pragma unroll
    for (int j = 0; j < 8; ++j) {
        a[j] += __shfl_xor(a[j], 16, 64);
        a[j] += __shfl_xor(a[j], 32, 64);
    }
    if (g == 0) {
        float dd = dinv[w];
        u32x4 o;
#pragma unroll
        for (int j = 0; j < 4; ++j) {
            float r0 = fmaxf(fmaf(a[2 * j],     dd, bias[c * 8 + 2 * j]),     0.f);
            float r1 = fmaxf(fmaf(a[2 * j + 1], dd, bias[c * 8 + 2 * j + 1]), 0.f);
            o[j] = (uint)f2bf(r0) | ((uint)f2bf(r1) << 16);
        }
        *(u32x4*)&outbf[(size_t)w * HD + c * 8] = o;
    }
}

// gather2 (OD=64): wave = 8 edge-groups x 8 col-lanes; f32 output.
__launch_bounds__(256)
__global__ void gather2_k(const ushort* __restrict__ feat, const int* __restrict__ csr,
                          const int* __restrict__ off, const float* __restrict__ dinv,
                          const float* __restrict__ bias, float* __restrict__ out) {
    const int w = (int)((blockIdx.x * 256 + threadIdx.x) >> 6);
    const int lane = threadIdx.x & 63;
    if (w >= NN) return;
    const int g = lane >> 3;          // edge group 0..7
    const int c = lane & 7;           // col chunk: cols c*8 .. c*8+7
    const int o0 = off[w], o1 = off[w + 1];

    float a[8];
    if (g == 0) {   // self row, counted exactly once
        u32x4 sv = *(const u32x4*)&feat[(size_t)w * OD + c * 8];
#pragma unroll
        for (int j = 0; j < 4; ++j) {
            a[2 * j]     = bf2f((ushort)sv[j]);
            a[2 * j + 1] = bf2f((ushort)(sv[j] >> 16));
        }
    } else {
#pragma unroll
        for (int j = 0; j < 8; ++j) a[j] = 0.f;
    }
    for (int i = o0; i < o1; i += 8) {
        int idx = i + g;
        if (idx < o1) {
            int s = csr[idx];
            u32x4 v = *(const u32x4*)&feat[(size_t)s * OD + c * 8];
#pragma unroll
            for (int j = 0; j < 4; ++j) {
                a[2 * j]     += bf2f((ushort)v[j]);
                a[2 * j + 1] += bf2f((ushort)(v[j] >> 16));
            }
        }
    }
#pragma unroll
    for (int j = 0; j < 8; ++j) {
        a[j] += __shfl_xor(a[j], 8, 64);
        a[j] += __shfl_xor(a[j], 16, 64);
        a[j] += __shfl_xor(a[j], 32, 64);
    }
    if (g == 0) {
        float dd = dinv[w];
        float4 lo, hi;
        lo.x = fmaf(a[0], dd, bias[c * 8 + 0]);
        lo.y = fmaf(a[1], dd, bias[c * 8 + 1]);
        lo.z = fmaf(a[2], dd, bias[c * 8 + 2]);
        lo.w = fmaf(a[3], dd, bias[c * 8 + 3]);
        hi.x = fmaf(a[4], dd, bias[c * 8 + 4]);
        hi.y = fmaf(a[5], dd, bias[c * 8 + 5]);
        hi.z = fmaf(a[6], dd, bias[c * 8 + 6]);
        hi.w = fmaf(a[7], dd, bias[c * 8 + 7]);
        *(float4*)&out[(size_t)w * OD + c * 8]     = lo;
        *(float4*)&out[(size_t)w * OD + c * 8 + 4] = hi;
    }
}

extern "C" void kernel_launch(void* const* d_in, const int* in_sizes, int n_in,
                              void* d_out, int out_size, void* d_ws, size_t ws_size,
                              hipStream_t stream) {
    const float* x   = (const float*)d_in[0];
    const int*   src = (const int*)d_in[1];
    const int*   dst = ((const int*)d_in[1]) + NE;
    const float* W1  = (const float*)d_in[2];
    const float* b1  = (const float*)d_in[3];
    const float* W2  = (const float*)d_in[4];
    const float* b2  = (const float*)d_in[5];
    float* out = (float*)d_out;

    // workspace carve-up (~36 MB), all chunks 16B-aligned
    float*  dinv   = (float*)d_ws;                       // 50048 f32
    uint*   W1p    = (uint*)(dinv + 50048);              // 16384 u32
    uint*   W2p    = W1p + 16384;                        // 4096 u32
    ushort* h1s_bf = (ushort*)(W2p + 4096);              // NN*HD bf16
    ushort* h_bf   = h1s_bf + (size_t)NN * HD;           // NN*HD bf16
    ushort* gs_bf  = h_bf + (size_t)NN * HD;             // NN*OD bf16
    int* deg_i  = (int*)(gs_bf + (size_t)NN * OD);       // 50048
    int* off    = deg_i + 50048;                         // 50052
    int* cursor = off + 50052;                           // 50048
    int* btot   = cursor + 50048;                        // 64
    int* csr    = btot + 64;                             // NE

    // CSR build + normalization
    hipMemsetAsync(deg_i, 0, 50048 * sizeof(int), stream);
    hipMemsetAsync(cursor, 0, 50048 * sizeof(int), stream);
    deg_count_i<<<(NE + 255) / 256, 256, 0, stream>>>(dst, deg_i);
    dinv_k<<<(NN + 255) / 256, 256, 0, stream>>>(deg_i, dinv);
    scan1_k<<<SCAN_NBLK, 1024, 0, stream>>>(deg_i, off, btot);
    scan2_k<<<1, 64, 0, stream>>>(btot, off);
    scan3_k<<<SCAN_NBLK, 1024, 0, stream>>>(off, btot);
    fill_k<<<(NE + 255) / 256, 256, 0, stream>>>(src, dst, off, cursor, csr);

    // weight prep (fragment-ordered bf16)
    prep_w_k<HD, IND><<<64, 256, 0, stream>>>(W1, W1p);
    prep_w_k<OD, HD><<<16, 256, 0, stream>>>(W2, W2p);

    // layer 1
    mfma_gemm_k<HD, IND, true><<<(NN + 63) / 64, 256, 0, stream>>>(x, W1p, dinv, h1s_bf, NN);
    gather1_k<<<(NN + 3) / 4, 256, 0, stream>>>(h1s_bf, csr, off, dinv, b1, h_bf);

    // layer 2
    mfma_gemm_k<OD, HD, false><<<(NN + 63) / 64, 256, 0, stream>>>(h_bf, W2p, dinv, gs_bf, NN);
    gather2_k<<<(NN + 3) / 4, 256, 0, stream>>>(gs_bf, csr, off, dinv, b2, out);
}

// Round 11
// 235.651 us; speedup vs baseline: 9.5664x; 1.1589x over previous
//
#include <hip/hip_runtime.h>

#define NN 50000
#define NE 800000
#define IND 256
#define HD 128
#define OD 64
#define SCAN_NBLK ((NN + 1023) / 1024)   // 49
#define DEG_BLKS ((NE + 255) / 256)      // 3125
#define G1_BLKS ((NN + 63) / 64)         // 782

typedef __attribute__((ext_vector_type(8))) short short8;
typedef __attribute__((ext_vector_type(4))) float f32x4;
typedef __attribute__((ext_vector_type(4))) uint u32x4;

static __device__ __forceinline__ ushort f2bf(float f) {
    uint u = __float_as_uint(f);
    u += 0x7fff + ((u >> 16) & 1);        // round-to-nearest-even
    return (ushort)(u >> 16);
}
static __device__ __forceinline__ float bf2f(ushort h) {
    return __uint_as_float(((uint)h) << 16);
}

// ---------- W prep body: f32 W[K][N] -> fragment-ordered bf16 pairs ----------
template<int N, int K>
static __device__ __forceinline__ void prep_w_body(const float* __restrict__ W,
                                                   uint* __restrict__ Wp, int i) {
    constexpr int NT = N / 16;
    constexpr int TOT = (K / 32) * NT * 256;
    if (i >= TOT) return;
    int region = i >> 8;
    int lane = (i >> 2) & 63;
    int jp = i & 3;
    int c8 = region / NT, nt = region % NT;
    int k = c8 * 32 + (lane >> 4) * 8 + jp * 2;
    int n = nt * 16 + (lane & 15);
    Wp[i] = (uint)f2bf(W[k * N + n]) | ((uint)f2bf(W[(k + 1) * N + n]) << 16);
}

// ---------- fused: degree histogram + per-edge rank + weight prep ----------
// rank[e] = old count = e's slot within its dst bucket (order irrelevant:
// CSR needs grouping, not stability).
__global__ void degrank_prep_k(const int* __restrict__ dst, int* __restrict__ deg,
                               int* __restrict__ rank,
                               const float* __restrict__ W1, uint* __restrict__ W1p,
                               const float* __restrict__ W2, uint* __restrict__ W2p) {
    int b = blockIdx.x;
    if (b < DEG_BLKS) {
        int e = b * 256 + threadIdx.x;
        if (e < NE) rank[e] = atomicAdd(&deg[dst[e]], 1);
    } else if (b < DEG_BLKS + 64) {
        prep_w_body<HD, IND>(W1, W1p, (b - DEG_BLKS) * 256 + threadIdx.x);
    } else {
        prep_w_body<OD, HD>(W2, W2p, (b - DEG_BLKS - 64) * 256 + threadIdx.x);
    }
}

// ---------- multi-block exclusive scan (scan1 also emits dinv) ----------

__launch_bounds__(1024)
__global__ void scan1_k(const int* __restrict__ deg, int* __restrict__ off,
                        int* __restrict__ btot, float* __restrict__ dinv) {
    __shared__ int wsum[16];
    const int tid = threadIdx.x, lane = tid & 63, wv = tid >> 6;
    const int idx = blockIdx.x * 1024 + tid;
    int v = (idx < NN) ? deg[idx] : 0;
    if (idx < NN) dinv[idx] = rsqrtf((float)v + 1.0f);   // +1 self-loop
    int inc = v;
#pragma unroll
    for (int ofs = 1; ofs < 64; ofs <<= 1) {
        int t = __shfl_up(inc, ofs, 64);
        if (lane >= ofs) inc += t;
    }
    if (lane == 63) wsum[wv] = inc;
    __syncthreads();
    int wprefix = 0;
#pragma unroll
    for (int w = 0; w < 16; ++w) wprefix += (w < wv) ? wsum[w] : 0;
    if (idx < NN) off[idx] = wprefix + inc - v;
    if (tid == 1023) btot[blockIdx.x] = wprefix + inc;
}

__launch_bounds__(64)
__global__ void scan2_k(int* __restrict__ btot, int* __restrict__ off) {
    const int lane = threadIdx.x;
    int v = (lane < SCAN_NBLK) ? btot[lane] : 0;
    int inc = v;
#pragma unroll
    for (int ofs = 1; ofs < 64; ofs <<= 1) {
        int t = __shfl_up(inc, ofs, 64);
        if (lane >= ofs) inc += t;
    }
    if (lane < SCAN_NBLK) btot[lane] = inc - v;
    if (lane == 63) off[NN] = inc;
}

__launch_bounds__(1024)
__global__ void scan3_k(int* __restrict__ off, const int* __restrict__ btot) {
    const int idx = blockIdx.x * 1024 + threadIdx.x;
    if (idx < NN) off[idx] += btot[blockIdx.x];
}

// ---------- fused: MFMA GEMM1 (x@W1, *dinv, ->bf16) + atomic-free CSR fill ----
// Blocks [0, G1_BLKS) compute gemm tiles; blocks [G1_BLKS, +DEG_BLKS) place
// edges: csr[off[dst]+rank] = src. Co-residency hides the MFMA work under the
// latency-bound scatter.
__launch_bounds__(256)
__global__ void gemm1_fill_k(const float* __restrict__ x, const uint* __restrict__ Wp,
                             const float* __restrict__ rs, ushort* __restrict__ Cbf,
                             const int* __restrict__ src, const int* __restrict__ dst,
                             const int* __restrict__ off, const int* __restrict__ rank,
                             int* __restrict__ csr) {
    constexpr int N = HD, K = IND;
    constexpr int NT = N / 16;
    constexpr int KH = K / 128;
    constexpr int NREG = 4 * NT;
    __shared__ uint bsl[NREG * 256];     // 32 KB

    if (blockIdx.x >= G1_BLKS) {         // ---- fill part (no atomics) ----
        int e = (int)(blockIdx.x - G1_BLKS) * 256 + threadIdx.x;
        if (e < NE) {
            int d = dst[e];
            csr[off[d] + rank[e]] = src[e];
        }
        return;
    }

    // ---- gemm part ----
    const int tid = threadIdx.x, lane = tid & 63, wv = tid >> 6;
    const int row = blockIdx.x * 64 + wv * 16 + (lane & 15);
    const int rowc = min(row, NN - 1);
    const int kl = (lane >> 4) * 8;

    f32x4 acc[NT];
#pragma unroll
    for (int t = 0; t < NT; ++t) acc[t] = (f32x4){0.f, 0.f, 0.f, 0.f};

    for (int h = 0; h < KH; ++h) {
        if (h) __syncthreads();
#pragma unroll
        for (int rg = wv; rg < NREG; rg += 4)
            __builtin_amdgcn_global_load_lds(
                (const uint __attribute__((address_space(1)))*)(Wp + (size_t)(h * NREG + rg) * 256 + lane * 4),
                (uint __attribute__((address_space(3)))*)&bsl[rg * 256], 16, 0, 0);
        __syncthreads();
#pragma unroll
        for (int c = 0; c < 4; ++c) {
            const int k0 = h * 128 + c * 32;
            f32x4 lo = *(const f32x4*)&x[(size_t)rowc * K + k0 + kl];
            f32x4 hi = *(const f32x4*)&x[(size_t)rowc * K + k0 + kl + 4];
            short8 af;
            af[0] = (short)f2bf(lo.x); af[1] = (short)f2bf(lo.y);
            af[2] = (short)f2bf(lo.z); af[3] = (short)f2bf(lo.w);
            af[4] = (short)f2bf(hi.x); af[5] = (short)f2bf(hi.y);
            af[6] = (short)f2bf(hi.z); af[7] = (short)f2bf(hi.w);
#pragma unroll
            for (int t = 0; t < NT; ++t) {
                short8 bf = *(const short8*)&bsl[(c * NT + t) * 256 + lane * 4];
                acc[t] = __builtin_amdgcn_mfma_f32_16x16x32_bf16(af, bf, acc[t], 0, 0, 0);
            }
        }
    }
    const int crow = blockIdx.x * 64 + wv * 16 + (lane >> 4) * 4;
#pragma unroll
    for (int t = 0; t < NT; ++t) {
        int col = t * 16 + (lane & 15);
#pragma unroll
        for (int r = 0; r < 4; ++r)
            if (crow + r < NN)
                Cbf[(size_t)(crow + r) * N + col] = f2bf(acc[t][r] * rs[crow + r]);
    }
}

// ---------- MFMA GEMM (layer 2): Cbf[M][N] = bf16( (A @ W) * rs[row] ) ------
template<int N, int K>
__launch_bounds__(256)
__global__ void mfma_gemm_k(const ushort* __restrict__ Ap, const uint* __restrict__ Wp,
                            const float* __restrict__ rs, ushort* __restrict__ Cbf,
                            int M) {
    constexpr int NT = N / 16;
    constexpr int KH = K / 128;
    constexpr int NREG = 4 * NT;
    __shared__ uint bsl[NREG * 256];
    const int tid = threadIdx.x, lane = tid & 63, wv = tid >> 6;
    const int row = blockIdx.x * 64 + wv * 16 + (lane & 15);
    const int rowc = min(row, M - 1);
    const int kl = (lane >> 4) * 8;

    f32x4 acc[NT];
#pragma unroll
    for (int t = 0; t < NT; ++t) acc[t] = (f32x4){0.f, 0.f, 0.f, 0.f};

    for (int h = 0; h < KH; ++h) {
        if (h) __syncthreads();
#pragma unroll
        for (int rg = wv; rg < NREG; rg += 4)
            __builtin_amdgcn_global_load_lds(
                (const uint __attribute__((address_space(1)))*)(Wp + (size_t)(h * NREG + rg) * 256 + lane * 4),
                (uint __attribute__((address_space(3)))*)&bsl[rg * 256], 16, 0, 0);
        __syncthreads();
#pragma unroll
        for (int c = 0; c < 4; ++c) {
            const int k0 = h * 128 + c * 32;
            short8 af = *(const short8*)&Ap[(size_t)rowc * K + k0 + kl];
#pragma unroll
            for (int t = 0; t < NT; ++t) {
                short8 bf = *(const short8*)&bsl[(c * NT + t) * 256 + lane * 4];
                acc[t] = __builtin_amdgcn_mfma_f32_16x16x32_bf16(af, bf, acc[t], 0, 0, 0);
            }
        }
    }
    const int crow = blockIdx.x * 64 + wv * 16 + (lane >> 4) * 4;
#pragma unroll
    for (int t = 0; t < NT; ++t) {
        int col = t * 16 + (lane & 15);
#pragma unroll
        for (int r = 0; r < 4; ++r)
            if (crow + r < M)
                Cbf[(size_t)(crow + r) * N + col] = f2bf(acc[t][r] * rs[crow + r]);
    }
}

// ---------- wide pull-mode gathers (unchanged from R10) ----------

__launch_bounds__(256)
__global__ void gather1_k(const ushort* __restrict__ feat, const int* __restrict__ csr,
                          const int* __restrict__ off, const float* __restrict__ dinv,
                          const float* __restrict__ bias, ushort* __restrict__ outbf) {
    const int w = (int)((blockIdx.x * 256 + threadIdx.x) >> 6);
    const int lane = threadIdx.x & 63;
    if (w >= NN) return;
    const int g = lane >> 4;          // edge group 0..3
    const int c = lane & 15;          // col chunk: cols c*8 .. c*8+7
    const int o0 = off[w], o1 = off[w + 1];

    float a[8];
    if (g == 0) {   // self row, counted exactly once
        u32x4 sv = *(const u32x4*)&feat[(size_t)w * HD + c * 8];
#pragma unroll
        for (int j = 0; j < 4; ++j) {
            a[2 * j]     = bf2f((ushort)sv[j]);
            a[2 * j + 1] = bf2f((ushort)(sv[j] >> 16));
        }
    } else {
#pragma unroll
        for (int j = 0; j < 8; ++j) a[j] = 0.f;
    }
    for (int i = o0; i < o1; i += 4) {
        int idx = i + g;
        if (idx < o1) {
            int s = csr[idx];
            u32x4 v = *(const u32x4*)&feat[(size_t)s * HD + c * 8];
#pragma unroll
            for (int j = 0; j < 4; ++j) {
                a[2 * j]     += bf2f((ushort)v[j]);
                a[2 * j + 1] += bf2f((ushort)(v[j] >> 16));
            }
        }
    }
#pragma unroll
    for (int j = 0; j < 8; ++j) {
        a[j] += __shfl_xor(a[j], 16, 64);
        a[j] += __shfl_xor(a[j], 32, 64);
    }
    if (g == 0) {
        float dd = dinv[w];
        u32x4 o;
#pragma unroll
        for (int j = 0; j < 4; ++j) {
            float r0 = fmaxf(fmaf(a[2 * j],     dd, bias[c * 8 + 2 * j]),     0.f);
            float r1 = fmaxf(fmaf(a[2 * j + 1], dd, bias[c * 8 + 2 * j + 1]), 0.f);
            o[j] = (uint)f2bf(r0) | ((uint)f2bf(r1) << 16);
        }
        *(u32x4*)&outbf[(size_t)w * HD + c * 8] = o;
    }
}

__launch_bounds__(256)
__global__ void gather2_k(const ushort* __restrict__ feat, const int* __restrict__ csr,
                          const int* __restrict__ off, const float* __restrict__ dinv,
                          const float* __restrict__ bias, float* __restrict__ out) {
    const int w = (int)((blockIdx.x * 256 + threadIdx.x) >> 6);
    const int lane = threadIdx.x & 63;
    if (w >= NN) return;
    const int g = lane >> 3;          // edge group 0..7
    const int c = lane & 7;           // col chunk: cols c*8 .. c*8+7
    const int o0 = off[w], o1 = off[w + 1];

    float a[8];
    if (g == 0) {
        u32x4 sv = *(const u32x4*)&feat[(size_t)w * OD + c * 8];
#pragma unroll
        for (int j = 0; j < 4; ++j) {
            a[2 * j]     = bf2f((ushort)sv[j]);
            a[2 * j + 1] = bf2f((ushort)(sv[j] >> 16));
        }
    } else {
#pragma unroll
        for (int j = 0; j < 8; ++j) a[j] = 0.f;
    }
    for (int i = o0; i < o1; i += 8) {
        int idx = i + g;
        if (idx < o1) {
            int s = csr[idx];
            u32x4 v = *(const u32x4*)&feat[(size_t)s * OD + c * 8];
#pragma unroll
            for (int j = 0; j < 4; ++j) {
                a[2 * j]     += bf2f((ushort)v[j]);
                a[2 * j + 1] += bf2f((ushort)(v[j] >> 16));
            }
        }
    }
#pragma unroll
    for (int j = 0; j < 8; ++j) {
        a[j] += __shfl_xor(a[j], 8, 64);
        a[j] += __shfl_xor(a[j], 16, 64);
        a[j] += __shfl_xor(a[j], 32, 64);
    }
    if (g == 0) {
        float dd = dinv[w];
        float4 lo, hi;
        lo.x = fmaf(a[0], dd, bias[c * 8 + 0]);
        lo.y = fmaf(a[1], dd, bias[c * 8 + 1]);
        lo.z = fmaf(a[2], dd, bias[c * 8 + 2]);
        lo.w = fmaf(a[3], dd, bias[c * 8 + 3]);
        hi.x = fmaf(a[4], dd, bias[c * 8 + 4]);
        hi.y = fmaf(a[5], dd, bias[c * 8 + 5]);
        hi.z = fmaf(a[6], dd, bias[c * 8 + 6]);
        hi.w = fmaf(a[7], dd, bias[c * 8 + 7]);
        *(float4*)&out[(size_t)w * OD + c * 8]     = lo;
        *(float4*)&out[(size_t)w * OD + c * 8 + 4] = hi;
    }
}

extern "C" void kernel_launch(void* const* d_in, const int* in_sizes, int n_in,
                              void* d_out, int out_size, void* d_ws, size_t ws_size,
                              hipStream_t stream) {
    const float* x   = (const float*)d_in[0];
    const int*   src = (const int*)d_in[1];
    const int*   dst = ((const int*)d_in[1]) + NE;
    const float* W1  = (const float*)d_in[2];
    const float* b1  = (const float*)d_in[3];
    const float* W2  = (const float*)d_in[4];
    const float* b2  = (const float*)d_in[5];
    float* out = (float*)d_out;

    // workspace carve-up (~40 MB), all chunks 16B-aligned
    float*  dinv   = (float*)d_ws;                       // 50048 f32
    uint*   W1p    = (uint*)(dinv + 50048);              // 16384 u32
    uint*   W2p    = W1p + 16384;                        // 4096 u32
    ushort* h1s_bf = (ushort*)(W2p + 4096);              // NN*HD bf16
    ushort* h_bf   = h1s_bf + (size_t)NN * HD;           // NN*HD bf16
    ushort* gs_bf  = h_bf + (size_t)NN * HD;             // NN*OD bf16
    int* deg_i  = (int*)(gs_bf + (size_t)NN * OD);       // 50048
    int* off    = deg_i + 50048;                         // 50052
    int* rank   = off + 50052;                           // NE
    int* btot   = rank + NE;                             // 64
    int* csr    = btot + 64;                             // NE

    // degree histogram (+ per-edge rank) + weight prep, one launch
    hipMemsetAsync(deg_i, 0, 50048 * sizeof(int), stream);
    degrank_prep_k<<<DEG_BLKS + 64 + 16, 256, 0, stream>>>(dst, deg_i, rank,
                                                           W1, W1p, W2, W2p);
    // scan (emits dinv in pass 1)
    scan1_k<<<SCAN_NBLK, 1024, 0, stream>>>(deg_i, off, btot, dinv);
    scan2_k<<<1, 64, 0, stream>>>(btot, off);
    scan3_k<<<SCAN_NBLK, 1024, 0, stream>>>(off, btot);

    // layer 1 GEMM fused with atomic-free CSR fill
    gemm1_fill_k<<<G1_BLKS + DEG_BLKS, 256, 0, stream>>>(x, W1p, dinv, h1s_bf,
                                                         src, dst, off, rank, csr);
    gather1_k<<<(NN + 3) / 4, 256, 0, stream>>>(h1s_bf, csr, off, dinv, b1, h_bf);

    // layer 2
    mfma_gemm_k<OD, HD><<<(NN + 63) / 64, 256, 0, stream>>>(h_bf, W2p, dinv, gs_bf, NN);
    gather2_k<<<(NN + 3) / 4, 256, 0, stream>>>(gs_bf, csr, off, dinv, b2, out);
}

// Round 16
// 217.226 us; speedup vs baseline: 10.3779x; 1.0848x over previous
//
#include <hip/hip_runtime.h>

#define NN 50000
#define NE 800000
#define IND 256
#define HD 128
#define OD 64
#define SCAN_NBLK ((NN + 1023) / 1024)   // 49
#define DEG_BLKS ((NE + 255) / 256)      // 3125
#define G1_BLKS ((NN + 63) / 64)         // 782
#define FIN_BLKS ((NN + 256) / 256)      // 196 (covers idx 0..NN)

typedef __attribute__((ext_vector_type(8))) short short8;
typedef __attribute__((ext_vector_type(4))) float f32x4;
typedef __attribute__((ext_vector_type(4))) uint u32x4;

static __device__ __forceinline__ ushort f2bf(float f) {
    uint u = __float_as_uint(f);
    u += 0x7fff + ((u >> 16) & 1);        // round-to-nearest-even
    return (ushort)(u >> 16);
}
static __device__ __forceinline__ float bf2f(ushort h) {
    return __uint_as_float(((uint)h) << 16);
}

// ---------- W prep: f32 W[K][N] -> fragment-ordered bf16 pairs ----------
template<int N, int K>
static __device__ __forceinline__ void prep_w_body(const float* __restrict__ W,
                                                   uint* __restrict__ Wp, int i) {
    constexpr int NT = N / 16;
    constexpr int TOT = (K / 32) * NT * 256;
    if (i >= TOT) return;
    int region = i >> 8;
    int lane = (i >> 2) & 63;
    int jp = i & 3;
    int c8 = region / NT, nt = region % NT;
    int k = c8 * 32 + (lane >> 4) * 8 + jp * 2;
    int n = nt * 16 + (lane & 15);
    Wp[i] = (uint)f2bf(W[k * N + n]) | ((uint)f2bf(W[(k + 1) * N + n]) << 16);
}

__global__ void prep_k(const float* __restrict__ W1, uint* __restrict__ W1p,
                       const float* __restrict__ W2, uint* __restrict__ W2p) {
    int b = blockIdx.x;
    if (b < 64) prep_w_body<HD, IND>(W1, W1p, b * 256 + threadIdx.x);
    else        prep_w_body<OD, HD>(W2, W2p, (b - 64) * 256 + threadIdx.x);
}

// ---------- mega: MFMA GEMM1 (x@W1 -> bf16, UNSCALED) + degree/rank ----------
// Blocks [0, G1_BLKS): gemm tiles.  Blocks [G1_BLKS, +DEG_BLKS): histogram
// with captured rank (rank[e] = slot of e within its dst bucket).
__launch_bounds__(256)
__global__ void mega_k(const float* __restrict__ x, const uint* __restrict__ Wp,
                       ushort* __restrict__ Cbf,
                       const int* __restrict__ dst, int* __restrict__ deg,
                       ushort* __restrict__ rank) {
    constexpr int N = HD, K = IND;
    constexpr int NT = N / 16;
    constexpr int KH = K / 128;
    constexpr int NREG = 4 * NT;
    __shared__ uint bsl[NREG * 256];     // 32 KB

    if (blockIdx.x >= G1_BLKS) {         // ---- degree + rank ----
        int e = (int)(blockIdx.x - G1_BLKS) * 256 + threadIdx.x;
        if (e < NE) rank[e] = (ushort)atomicAdd(&deg[dst[e]], 1);
        return;
    }

    // ---- gemm part (no row scale) ----
    const int tid = threadIdx.x, lane = tid & 63, wv = tid >> 6;
    const int row = blockIdx.x * 64 + wv * 16 + (lane & 15);
    const int rowc = min(row, NN - 1);
    const int kl = (lane >> 4) * 8;

    f32x4 acc[NT];
#pragma unroll
    for (int t = 0; t < NT; ++t) acc[t] = (f32x4){0.f, 0.f, 0.f, 0.f};

    for (int h = 0; h < KH; ++h) {
        if (h) __syncthreads();
#pragma unroll
        for (int rg = wv; rg < NREG; rg += 4)
            __builtin_amdgcn_global_load_lds(
                (const uint __attribute__((address_space(1)))*)(Wp + (size_t)(h * NREG + rg) * 256 + lane * 4),
                (uint __attribute__((address_space(3)))*)&bsl[rg * 256], 16, 0, 0);
        __syncthreads();
#pragma unroll
        for (int c = 0; c < 4; ++c) {
            const int k0 = h * 128 + c * 32;
            f32x4 lo = *(const f32x4*)&x[(size_t)rowc * K + k0 + kl];
            f32x4 hi = *(const f32x4*)&x[(size_t)rowc * K + k0 + kl + 4];
            short8 af;
            af[0] = (short)f2bf(lo.x); af[1] = (short)f2bf(lo.y);
            af[2] = (short)f2bf(lo.z); af[3] = (short)f2bf(lo.w);
            af[4] = (short)f2bf(hi.x); af[5] = (short)f2bf(hi.y);
            af[6] = (short)f2bf(hi.z); af[7] = (short)f2bf(hi.w);
#pragma unroll
            for (int t = 0; t < NT; ++t) {
                short8 bf = *(const short8*)&bsl[(c * NT + t) * 256 + lane * 4];
                acc[t] = __builtin_amdgcn_mfma_f32_16x16x32_bf16(af, bf, acc[t], 0, 0, 0);
            }
        }
    }
    const int crow = blockIdx.x * 64 + wv * 16 + (lane >> 4) * 4;
#pragma unroll
    for (int t = 0; t < NT; ++t) {
        int col = t * 16 + (lane & 15);
#pragma unroll
        for (int r = 0; r < 4; ++r)
            if (crow + r < NN)
                Cbf[(size_t)(crow + r) * N + col] = f2bf(acc[t][r]);
    }
}

// ---------- scans ----------

__launch_bounds__(1024)
__global__ void scan1_k(const int* __restrict__ deg, int* __restrict__ off,
                        int* __restrict__ btot, float* __restrict__ dinv) {
    __shared__ int wsum[16];
    const int tid = threadIdx.x, lane = tid & 63, wv = tid >> 6;
    const int idx = blockIdx.x * 1024 + tid;
    int v = (idx < NN) ? deg[idx] : 0;
    if (idx < NN) dinv[idx] = rsqrtf((float)v + 1.0f);   // +1 self-loop
    int inc = v;
#pragma unroll
    for (int ofs = 1; ofs < 64; ofs <<= 1) {
        int t = __shfl_up(inc, ofs, 64);
        if (lane >= ofs) inc += t;
    }
    if (lane == 63) wsum[wv] = inc;
    __syncthreads();
    int wprefix = 0;
#pragma unroll
    for (int w = 0; w < 16; ++w) wprefix += (w < wv) ? wsum[w] : 0;
    if (idx < NN) off[idx] = wprefix + inc - v;           // block-local exclusive
    if (tid == 1023) btot[blockIdx.x] = wprefix + inc;
}

__launch_bounds__(64)
__global__ void scan2_k(int* __restrict__ btot, int* __restrict__ off) {
    const int lane = threadIdx.x;
    int v = (lane < SCAN_NBLK) ? btot[lane] : 0;
    int inc = v;
#pragma unroll
    for (int ofs = 1; ofs < 64; ofs <<= 1) {
        int t = __shfl_up(inc, ofs, 64);
        if (lane >= ofs) inc += t;
    }
    if (lane < SCAN_NBLK) btot[lane] = inc - v;           // exclusive block offsets
    if (lane == 63) off[NN] = inc;                        // grand total
}

// ---------- fill (atomic-free, inline scan3) + off2 finalize ----------
// Blocks [0, DEG_BLKS): csr[offF(d) + rank[e]] = src[e], offF = off + btot.
// Blocks [DEG_BLKS, +FIN_BLKS): off2[idx] = final offsets for the gathers.
__global__ void fillf_k(const int* __restrict__ src, const int* __restrict__ dst,
                        const int* __restrict__ off, const int* __restrict__ btot,
                        const ushort* __restrict__ rank, ushort* __restrict__ csr,
                        int* __restrict__ off2) {
    int b = blockIdx.x;
    if (b < DEG_BLKS) {
        int e = b * 256 + threadIdx.x;
        if (e < NE) {
            int d = dst[e];
            int o = off[d] + btot[d >> 10];
            csr[o + rank[e]] = (ushort)src[e];
        }
    } else {
        int idx = (b - DEG_BLKS) * 256 + threadIdx.x;
        if (idx < NN) off2[idx] = off[idx] + btot[idx >> 10];
        else if (idx == NN) off2[NN] = off[NN];
    }
}

// ---------- MFMA GEMM (layer 2): Cbf = bf16( (A @ W) * rs[row] ) ----------
template<int N, int K>
__launch_bounds__(256)
__global__ void mfma_gemm_k(const ushort* __restrict__ Ap, const uint* __restrict__ Wp,
                            const float* __restrict__ rs, ushort* __restrict__ Cbf,
                            int M) {
    constexpr int NT = N / 16;
    constexpr int KH = K / 128;
    constexpr int NREG = 4 * NT;
    __shared__ uint bsl[NREG * 256];
    const int tid = threadIdx.x, lane = tid & 63, wv = tid >> 6;
    const int row = blockIdx.x * 64 + wv * 16 + (lane & 15);
    const int rowc = min(row, M - 1);
    const int kl = (lane >> 4) * 8;

    f32x4 acc[NT];
#pragma unroll
    for (int t = 0; t < NT; ++t) acc[t] = (f32x4){0.f, 0.f, 0.f, 0.f};

    for (int h = 0; h < KH; ++h) {
        if (h) __syncthreads();
#pragma unroll
        for (int rg = wv; rg < NREG; rg += 4)
            __builtin_amdgcn_global_load_lds(
                (const uint __attribute__((address_space(1)))*)(Wp + (size_t)(h * NREG + rg) * 256 + lane * 4),
                (uint __attribute__((address_space(3)))*)&bsl[rg * 256], 16, 0, 0);
        __syncthreads();
#pragma unroll
        for (int c = 0; c < 4; ++c) {
            const int k0 = h * 128 + c * 32;
            short8 af = *(const short8*)&Ap[(size_t)rowc * K + k0 + kl];
#pragma unroll
            for (int t = 0; t < NT; ++t) {
                short8 bf = *(const short8*)&bsl[(c * NT + t) * 256 + lane * 4];
                acc[t] = __builtin_amdgcn_mfma_f32_16x16x32_bf16(af, bf, acc[t], 0, 0, 0);
            }
        }
    }
    const int crow = blockIdx.x * 64 + wv * 16 + (lane >> 4) * 4;
#pragma unroll
    for (int t = 0; t < NT; ++t) {
        int col = t * 16 + (lane & 15);
#pragma unroll
        for (int r = 0; r < 4; ++r)
            if (crow + r < M)
                Cbf[(size_t)(crow + r) * N + col] = f2bf(acc[t][r] * rs[crow + r]);
    }
}

// ---------- gather1: unscaled feat, dinv[s] applied per row ----------
// h[w] = relu( (sum_e feat[s_e]*dinv[s_e] + feat[w]*dinv[w]) * dinv[w] + b1 )
__launch_bounds__(256)
__global__ void gather1_k(const ushort* __restrict__ feat, const ushort* __restrict__ csr,
                          const int* __restrict__ off, const float* __restrict__ dinv,
                          const float* __restrict__ bias, ushort* __restrict__ outbf) {
    const int w = (int)((blockIdx.x * 256 + threadIdx.x) >> 6);
    const int lane = threadIdx.x & 63;
    if (w >= NN) return;
    const int g = lane >> 4;          // edge group 0..3
    const int c = lane & 15;          // col chunk: cols c*8 .. c*8+7
    const int o0 = off[w], o1 = off[w + 1];
    const float dd = dinv[w];

    float a[8];
    if (g == 0) {   // self row * dinv[w], counted exactly once
        u32x4 sv = *(const u32x4*)&feat[(size_t)w * HD + c * 8];
#pragma unroll
        for (int j = 0; j < 4; ++j) {
            a[2 * j]     = bf2f((ushort)sv[j]) * dd;
            a[2 * j + 1] = bf2f((ushort)(sv[j] >> 16)) * dd;
        }
    } else {
#pragma unroll
        for (int j = 0; j < 8; ++j) a[j] = 0.f;
    }
    for (int i = o0; i < o1; i += 4) {
        int idx = i + g;
        if (idx < o1) {
            int s = csr[idx];
            float ds = dinv[s];
            u32x4 v = *(const u32x4*)&feat[(size_t)s * HD + c * 8];
#pragma unroll
            for (int j = 0; j < 4; ++j) {
                a[2 * j]     = fmaf(bf2f((ushort)v[j]),         ds, a[2 * j]);
                a[2 * j + 1] = fmaf(bf2f((ushort)(v[j] >> 16)), ds, a[2 * j + 1]);
            }
        }
    }
#pragma unroll
    for (int j = 0; j < 8; ++j) {
        a[j] += __shfl_xor(a[j], 16, 64);
        a[j] += __shfl_xor(a[j], 32, 64);
    }
    if (g == 0) {
        u32x4 o;
#pragma unroll
        for (int j = 0; j < 4; ++j) {
            float r0 = fmaxf(fmaf(a[2 * j],     dd, bias[c * 8 + 2 * j]),     0.f);
            float r1 = fmaxf(fmaf(a[2 * j + 1], dd, bias[c * 8 + 2 * j + 1]), 0.f);
            o[j] = (uint)f2bf(r0) | ((uint)f2bf(r1) << 16);
        }
        *(u32x4*)&outbf[(size_t)w * HD + c * 8] = o;
    }
}

// ---------- gather2: pre-scaled feat (unchanged semantics) ----------
__launch_bounds__(256)
__global__ void gather2_k(const ushort* __restrict__ feat, const ushort* __restrict__ csr,
                          const int* __restrict__ off, const float* __restrict__ dinv,
                          const float* __restrict__ bias, float* __restrict__ out) {
    const int w = (int)((blockIdx.x * 256 + threadIdx.x) >> 6);
    const int lane = threadIdx.x & 63;
    if (w >= NN) return;
    const int g = lane >> 3;          // edge group 0..7
    const int c = lane & 7;           // col chunk: cols c*8 .. c*8+7
    const int o0 = off[w], o1 = off[w + 1];

    float a[8];
    if (g == 0) {
        u32x4 sv = *(const u32x4*)&feat[(size_t)w * OD + c * 8];
#pragma unroll
        for (int j = 0; j < 4; ++j) {
            a[2 * j]     = bf2f((ushort)sv[j]);
            a[2 * j + 1] = bf2f((ushort)(sv[j] >> 16));
        }
    } else {
#pragma unroll
        for (int j = 0; j < 8; ++j) a[j] = 0.f;
    }
    for (int i = o0; i < o1; i += 8) {
        int idx = i + g;
        if (idx < o1) {
            int s = csr[idx];
            u32x4 v = *(const u32x4*)&feat[(size_t)s * OD + c * 8];
#pragma unroll
            for (int j = 0; j < 4; ++j) {
                a[2 * j]     += bf2f((ushort)v[j]);
                a[2 * j + 1] += bf2f((ushort)(v[j] >> 16));
            }
        }
    }
#pragma unroll
    for (int j = 0; j < 8; ++j) {
        a[j] += __shfl_xor(a[j], 8, 64);
        a[j] += __shfl_xor(a[j], 16, 64);
        a[j] += __shfl_xor(a[j], 32, 64);
    }
    if (g == 0) {
        float dd = dinv[w];
        float4 lo, hi;
        lo.x = fmaf(a[0], dd, bias[c * 8 + 0]);
        lo.y = fmaf(a[1], dd, bias[c * 8 + 1]);
        lo.z = fmaf(a[2], dd, bias[c * 8 + 2]);
        lo.w = fmaf(a[3], dd, bias[c * 8 + 3]);
        hi.x = fmaf(a[4], dd, bias[c * 8 + 4]);
        hi.y = fmaf(a[5], dd, bias[c * 8 + 5]);
        hi.z = fmaf(a[6], dd, bias[c * 8 + 6]);
        hi.w = fmaf(a[7], dd, bias[c * 8 + 7]);
        *(float4*)&out[(size_t)w * OD + c * 8]     = lo;
        *(float4*)&out[(size_t)w * OD + c * 8 + 4] = hi;
    }
}

extern "C" void kernel_launch(void* const* d_in, const int* in_sizes, int n_in,
                              void* d_out, int out_size, void* d_ws, size_t ws_size,
                              hipStream_t stream) {
    const float* x   = (const float*)d_in[0];
    const int*   src = (const int*)d_in[1];
    const int*   dst = ((const int*)d_in[1]) + NE;
    const float* W1  = (const float*)d_in[2];
    const float* b1  = (const float*)d_in[3];
    const float* W2  = (const float*)d_in[4];
    const float* b2  = (const float*)d_in[5];
    float* out = (float*)d_out;

    // workspace carve-up (~36 MB), all chunks 16B-aligned
    float*  dinv   = (float*)d_ws;                       // 50048 f32
    uint*   W1p    = (uint*)(dinv + 50048);              // 16384 u32
    uint*   W2p    = W1p + 16384;                        // 4096 u32
    ushort* h1u_bf = (ushort*)(W2p + 4096);              // NN*HD bf16 (unscaled)
    ushort* h_bf   = h1u_bf + (size_t)NN * HD;           // NN*HD bf16
    ushort* gs_bf  = h_bf + (size_t)NN * HD;             // NN*OD bf16
    int* deg_i  = (int*)(gs_bf + (size_t)NN * OD);       // 50048
    int* off    = deg_i + 50048;                         // 50052
    int* off2   = off + 50052;                           // 50052
    int* btot   = off2 + 50052;                          // 64
    ushort* rank = (ushort*)(btot + 64);                 // NE ushort
    ushort* csr  = rank + NE;                            // NE ushort

    hipMemsetAsync(deg_i, 0, 50048 * sizeof(int), stream);
    prep_k<<<80, 256, 0, stream>>>(W1, W1p, W2, W2p);

    // gemm1 (unscaled) fused with degree histogram + rank capture
    mega_k<<<G1_BLKS + DEG_BLKS, 256, 0, stream>>>(x, W1p, h1u_bf, dst, deg_i, rank);

    scan1_k<<<SCAN_NBLK, 1024, 0, stream>>>(deg_i, off, btot, dinv);
    scan2_k<<<1, 64, 0, stream>>>(btot, off);

    // atomic-free CSR fill (inline scan3) + off2 finalize
    fillf_k<<<DEG_BLKS + FIN_BLKS, 256, 0, stream>>>(src, dst, off, btot, rank, csr, off2);

    gather1_k<<<(NN + 3) / 4, 256, 0, stream>>>(h1u_bf, csr, off2, dinv, b1, h_bf);

    mfma_gemm_k<OD, HD><<<(NN + 63) / 64, 256, 0, stream>>>(h_bf, W2p, dinv, gs_bf, NN);
    gather2_k<<<(NN + 3) / 4, 256, 0, stream>>>(gs_bf, csr, off2, dinv, b2, out);
}